// Round 16
// baseline (397.728 us; speedup 1.0000x reference)
//
#include <hip/hip_runtime.h>
#include <hip/hip_bf16.h>

typedef __attribute__((ext_vector_type(8))) short short8;
typedef __attribute__((ext_vector_type(4))) float f32x4;

__device__ __forceinline__ void gload_lds16(const void* g, void* l) {
    __builtin_amdgcn_global_load_lds(
        (const __attribute__((address_space(1))) void*)g,
        (__attribute__((address_space(3))) void*)l, 16, 0, 0);
}

__device__ __forceinline__ float gelu_exact(float x) {
    return 0.5f * x * (1.0f + erff(x * 0.70710678118654752f));
}
__device__ __forceinline__ unsigned short f2b_raw(float f) {
    __hip_bfloat16 h = __float2bfloat16(f);
    return *reinterpret_cast<unsigned short*>(&h);
}
__device__ __forceinline__ float tofloat(float f) { return f; }
__device__ __forceinline__ float tofloat(__hip_bfloat16 h) { return __bfloat162float(h); }

// ---------------- conv 3x3 (C=1) + exact GELU over 32x32 patches ----------------
__global__ __launch_bounds__(256) void conv_qkv(
    const float* __restrict__ x,
    const float* __restrict__ qw, const float* __restrict__ kw, const float* __restrict__ vw,
    __hip_bfloat16* __restrict__ qb, __hip_bfloat16* __restrict__ kb, __hip_bfloat16* __restrict__ vb)
{
    __shared__ float img[1024];
    const int bid = blockIdx.x;            // b*1024 + n
    const int b = bid >> 10, n = bid & 1023;
    const float* xr = x + (long)bid * 1024;
    for (int i = threadIdx.x; i < 1024; i += 256) img[i] = xr[i];
    __syncthreads();

    float wq[9], wk[9], wv[9];
    #pragma unroll
    for (int i = 0; i < 9; ++i) { wq[i] = qw[i]; wk[i] = kw[i]; wv[i] = vw[i]; }

    for (int q = 0; q < 4; ++q) {
        const int p = q * 256 + threadIdx.x;    // 0..1023 spatial
        const int r = p >> 5, c = p & 31;
        float sq = 0.f, sk = 0.f, sv = 0.f;
        #pragma unroll
        for (int dy = 0; dy < 3; ++dy) {
            const int rr = r + dy - 1;
            if (rr < 0 || rr > 31) continue;
            #pragma unroll
            for (int dx = 0; dx < 3; ++dx) {
                const int cc = c + dx - 1;
                if (cc < 0 || cc > 31) continue;
                const float px = img[rr * 32 + cc];
                sq += px * wq[dy * 3 + dx];
                sk += px * wk[dy * 3 + dx];
                sv += px * wv[dy * 3 + dx];
            }
        }
        sq = gelu_exact(sq); sk = gelu_exact(sk); sv = gelu_exact(sv);
        const int h = p >> 7, d = p & 127;
        const long off = ((long)(b * 8 + h) * 1024 + n) * 128 + d;
        qb[off] = __float2bfloat16(sq);
        kb[off] = __float2bfloat16(sk);
        vb[off] = __float2bfloat16(sv);
    }
}

// ---------------- tiled transpose + cast to bf16 ----------------
template <typename Tin>
__global__ __launch_bounds__(256) void transpose_cast(
    const Tin* __restrict__ in, __hip_bfloat16* __restrict__ out,
    int R, int Cc, long inz, long outz)
{
    __shared__ float tile[32][33];
    const long z = blockIdx.z;
    const int c0 = blockIdx.x * 32, r0 = blockIdx.y * 32;
    const int tx = threadIdx.x & 31, ty = threadIdx.x >> 5;   // 32 x 8
    const Tin* ip = in + z * inz;
    #pragma unroll
    for (int i = 0; i < 32; i += 8)
        tile[ty + i][tx] = tofloat(ip[(long)(r0 + ty + i) * Cc + (c0 + tx)]);
    __syncthreads();
    __hip_bfloat16* op = out + z * outz;
    #pragma unroll
    for (int i = 0; i < 32; i += 8)
        op[(long)(c0 + ty + i) * R + (r0 + tx)] = __float2bfloat16(tile[tx][ty + i]);
}

// ---------------- fused QK^T + exp (softmax numerator) + row-sum ----------------
__global__ __launch_bounds__(256, 2) void qk_softmax(
    const __hip_bfloat16* __restrict__ qb, const __hip_bfloat16* __restrict__ kb,
    __hip_bfloat16* __restrict__ Pun, float* __restrict__ linv)
{
    __shared__ __align__(16) char smem[74240];
    char* As = smem;                                       // [128][128] bf16 swizzled
    char* Bs = smem + 32768;                               // [128][128] bf16 swizzled
    __hip_bfloat16* pbuf = (__hip_bfloat16*)(smem + 65536); // [32][136] bounce
    float* lred = (float*)(smem + 65536);                  // reuse after last bounce

    const int tid = threadIdx.x;
    const int rt = blockIdx.x, z = blockIdx.y;
    const char* Ag = (const char*)(qb + ((long)z * 1024 + rt * 128) * 128);
    const char* Bg = (const char*)(kb + (long)z * 1024 * 128);

    int gsrc[8], pphys[8];
    #pragma unroll
    for (int i = 0; i < 8; ++i) {
        const int p = i * 4096 + tid * 16;
        const int L = p ^ (((p >> 8) & 7) << 4);   // involution
        pphys[i] = p; gsrc[i] = L;
    }
    auto STAGE = [&](const char* gb, char* lb) {
        #pragma unroll
        for (int i = 0; i < 8; ++i) gload_lds16(gb + gsrc[i], lb + pphys[i]);
    };
    auto LD8 = [&](const char* buf, int L) -> short8 {
        const int ph = L ^ (((L >> 8) & 7) << 4);
        return *(const short8*)(buf + ph);
    };

    const int lane = tid & 63, wave = tid >> 6;
    const int wr = (wave >> 1) * 64, wc = (wave & 1) * 64;
    const int fr = lane & 15, kl = lane >> 4;

    STAGE(Ag, As);
    STAGE(Bg, Bs);
    __syncthreads();

    short8 af[4][4];
    #pragma unroll
    for (int m = 0; m < 4; ++m)
        #pragma unroll
        for (int kk = 0; kk < 4; ++kk)
            af[m][kk] = LD8(As, (wr + m * 16 + fr) * 256 + (kl * 8 + kk * 32) * 2);

    float lacc[4][4];
    #pragma unroll
    for (int m = 0; m < 4; ++m)
        #pragma unroll
        for (int r = 0; r < 4; ++r) lacc[m][r] = 0.f;

    const float SCALE = 0.08838834764831843f;   // 128^-0.5

    for (int c = 0; c < 8; ++c) {
        f32x4 acc[4][4];
        #pragma unroll
        for (int m = 0; m < 4; ++m)
            #pragma unroll
            for (int n = 0; n < 4; ++n) acc[m][n] = (f32x4){0.f, 0.f, 0.f, 0.f};

        #pragma unroll
        for (int kk = 0; kk < 4; ++kk) {
            short8 bf[4];
            #pragma unroll
            for (int n = 0; n < 4; ++n)
                bf[n] = LD8(Bs, (wc + n * 16 + fr) * 256 + (kl * 8 + kk * 32) * 2);
            #pragma unroll
            for (int m = 0; m < 4; ++m)
                #pragma unroll
                for (int n = 0; n < 4; ++n)
                    acc[m][n] = __builtin_amdgcn_mfma_f32_16x16x32_bf16(af[m][kk], bf[n], acc[m][n], 0, 0, 0);
        }

        // exp in-register + row-sum accumulate (single fast exp)
        #pragma unroll
        for (int m = 0; m < 4; ++m) {
            #pragma unroll
            for (int n = 0; n < 4; ++n)
                #pragma unroll
                for (int r = 0; r < 4; ++r)
                    acc[m][n][r] = __expf(acc[m][n][r] * SCALE);
            #pragma unroll
            for (int r = 0; r < 4; ++r)
                lacc[m][r] += (acc[m][0][r] + acc[m][1][r]) + (acc[m][2][r] + acc[m][3][r]);
        }

        // bounce 32-row rounds -> coalesced bf16 NT stores; overlap next B stage
        #pragma unroll
        for (int q2 = 0; q2 < 4; ++q2) {
            if ((wave >> 1) == (q2 >> 1)) {
                #pragma unroll
                for (int mm = 0; mm < 2; ++mm) {
                    const int m = (q2 & 1) * 2 + mm;
                    const int lr0 = m * 16 + kl * 4 - (q2 & 1) * 32;
                    #pragma unroll
                    for (int n = 0; n < 4; ++n)
                        #pragma unroll
                        for (int r = 0; r < 4; ++r)
                            pbuf[(lr0 + r) * 136 + wc + n * 16 + fr] = __float2bfloat16(acc[m][n][r]);
                }
            }
            __syncthreads();
            if (q2 == 0 && c < 7) STAGE(Bg + (c + 1) * 32768, Bs);  // Bs reads retired
            #pragma unroll
            for (int p = 0; p < 2; ++p) {
                const int idx = (tid + p * 256) * 8;
                const int row = idx >> 7, col = idx & 127;
                short8 s = *(const short8*)&pbuf[row * 136 + col];
                __builtin_nontemporal_store(s,
                    (short8*)&Pun[((long)z * 1024 + rt * 128 + q2 * 32 + row) * 1024 + c * 128 + col]);
            }
            __syncthreads();   // final one drains vmcnt -> new Bs visible next iter
        }
    }

    // l reduction
    #pragma unroll
    for (int m = 0; m < 4; ++m)
        #pragma unroll
        for (int r = 0; r < 4; ++r) {
            float v = lacc[m][r];
            v += __shfl_xor(v, 1); v += __shfl_xor(v, 2);
            v += __shfl_xor(v, 4); v += __shfl_xor(v, 8);
            lacc[m][r] = v;
        }
    __syncthreads();
    if (fr == 0) {
        #pragma unroll
        for (int m = 0; m < 4; ++m)
            #pragma unroll
            for (int r = 0; r < 4; ++r)
                lred[(wr + m * 16 + kl * 4 + r) * 2 + (wave & 1)] = lacc[m][r];
    }
    __syncthreads();
    if (tid < 128) {
        const float s = lred[tid * 2] + lred[tid * 2 + 1];
        linv[(long)z * 1024 + rt * 128 + tid] = 1.0f / s;
    }
}

// ---------------- reatten 256x256 GEMM, BK=32, 4-buf depth-2, fp32-only output ----------------
// attnb write DROPPED (-134 MB): PV consumes attnF fp32 directly (r5-validated path).
__global__ __launch_bounds__(512, 2) void gemm_reatten_256(
    const __hip_bfloat16* __restrict__ Sall, const __hip_bfloat16* __restrict__ Wt,
    float* __restrict__ Cout,
    const float* __restrict__ bg, const float* __restrict__ rb, const float* __restrict__ bb,
    const float* __restrict__ linv)
{
    __shared__ __align__(16) char smem[131072];
    char* ldsA = smem;            // 4 x 16384 (A: [256 rows][32 k] bf16, swizzled)
    char* ldsB = smem + 65536;    // 4 x 16384

    const int tid = threadIdx.x;
    const int z = blockIdx.z, tileM = blockIdx.x, tileN = blockIdx.y;
    const char* Ab = (const char*)(Sall + (long)z * 1048576 + (long)tileM * 256 * 1024);
    const char* Bb = (const char*)(Wt + (long)tileN * 256 * 1024);

    int grow[2], goff[2], pphys[2];
    #pragma unroll
    for (int i = 0; i < 2; ++i) {
        const int p = i * 8192 + tid * 16;
        const int l = p ^ (((p >> 7) & 3) << 4);   // involution
        pphys[i] = p; grow[i] = l >> 6; goff[i] = l & 63;
    }
    auto STAGE = [&](const char* gb, char* lb, int kt) {
        #pragma unroll
        for (int i = 0; i < 2; ++i)
            gload_lds16(gb + (long)grow[i] * 2048 + kt * 64 + goff[i], lb + pphys[i]);
    };

    const int lane = tid & 63, wid = tid >> 6;
    const int wrM = wid >> 2, wcn = wid & 3;        // 2 x 4 wave grid
    const int fr = lane & 15, kl = lane >> 4;
    const int frbase = fr * 64 + kl * 16;

    auto LD8 = [&](const char* buf, int L) -> short8 {
        const int ph = L ^ (((L >> 7) & 3) << 4);
        return *(const short8*)(buf + ph);
    };

    f32x4 acc[8][4];
    #pragma unroll
    for (int m = 0; m < 8; ++m)
        #pragma unroll
        for (int n = 0; n < 4; ++n) acc[m][n] = (f32x4){0.f, 0.f, 0.f, 0.f};

    STAGE(Ab, ldsA, 0);          STAGE(Bb, ldsB, 0);
    STAGE(Ab, ldsA + 16384, 1);  STAGE(Bb, ldsB + 16384, 1);
    asm volatile("s_waitcnt vmcnt(4)" ::: "memory");
    __builtin_amdgcn_sched_barrier(0);
    __builtin_amdgcn_s_barrier();
    __builtin_amdgcn_sched_barrier(0);

    #pragma unroll 1
    for (int t = 0; t < 32; ++t) {
        char* bufA = ldsA + (t & 3) * 16384;
        char* bufB = ldsB + (t & 3) * 16384;
        const int t2 = t + 2;
        char* nA = ldsA + (t2 & 3) * 16384;
        char* nB = ldsB + (t2 & 3) * 16384;

        short8 bf[4], af[4], ag[4];
        #pragma unroll
        for (int n = 0; n < 4; ++n) bf[n] = LD8(bufB, ((wcn * 64 + n * 16) * 64) + frbase);
        #pragma unroll
        for (int j = 0; j < 4; ++j) af[j] = LD8(bufA, ((wrM * 128 + j * 16) * 64) + frbase);
        if (t2 < 32) STAGE(Ab, nA, t2);
        __builtin_amdgcn_s_setprio(1);
        #pragma unroll
        for (int j = 0; j < 4; ++j)
            #pragma unroll
            for (int n = 0; n < 4; ++n)
                acc[j][n] = __builtin_amdgcn_mfma_f32_16x16x32_bf16(af[j], bf[n], acc[j][n], 0, 0, 0);
        __builtin_amdgcn_s_setprio(0);

        #pragma unroll
        for (int j = 0; j < 4; ++j) ag[j] = LD8(bufA, ((wrM * 128 + 64 + j * 16) * 64) + frbase);
        if (t2 < 32) STAGE(Bb, nB, t2);
        __builtin_amdgcn_s_setprio(1);
        #pragma unroll
        for (int j = 0; j < 4; ++j)
            #pragma unroll
            for (int n = 0; n < 4; ++n)
                acc[4 + j][n] = __builtin_amdgcn_mfma_f32_16x16x32_bf16(ag[j], bf[n], acc[4 + j][n], 0, 0, 0);
        __builtin_amdgcn_s_setprio(0);

        if (t < 30)       { asm volatile("s_waitcnt vmcnt(4)" ::: "memory"); }
        else if (t == 30) { asm volatile("s_waitcnt vmcnt(0)" ::: "memory"); }
        __builtin_amdgcn_sched_barrier(0);
        __builtin_amdgcn_s_barrier();
        __builtin_amdgcn_sched_barrier(0);
    }

    // ---- epilogue: row-scale (1/l) + BN affine + LDS bounce (64x260) + fp32 NT stores ----
    __syncthreads();
    float* cbuf = (float*)smem;
    const float bninv = rsqrtf(1.0f + 1e-3f);
    float alpha[4], addv[4];
    #pragma unroll
    for (int n = 0; n < 4; ++n) {
        const int col = tileN * 256 + wcn * 64 + n * 16 + fr;
        const float g = bg[col];
        alpha[n] = g * bninv;
        addv[n] = rb[col] * alpha[n] + bb[col];
    }
    const float* linvz = linv + (long)z * 1024 + tileM * 256 + wrM * 128 + kl * 4;
    f32x4 lr[8];
    #pragma unroll
    for (int mf = 0; mf < 8; ++mf) lr[mf] = *(const f32x4*)(linvz + mf * 16);

    const int srow = tid >> 3, cseg = (tid & 7) * 4;
    #pragma unroll
    for (int c = 0; c < 4; ++c) {
        if (wrM == (c >> 1)) {
            #pragma unroll
            for (int j = 0; j < 4; ++j) {
                const int mf = (c & 1) * 4 + j;
                const int lrow0 = j * 16 + kl * 4;
                #pragma unroll
                for (int n = 0; n < 4; ++n)
                    #pragma unroll
                    for (int r = 0; r < 4; ++r)
                        cbuf[(lrow0 + r) * 260 + wcn * 64 + n * 16 + fr] =
                            acc[mf][n][r] * (lr[mf][r] * alpha[n]) + addv[n];
            }
        }
        __syncthreads();
        const long gro = (long)(tileM * 256 + c * 64 + srow);
        float* gp = Cout + (long)z * 1048576 + gro * 1024 + tileN * 256;
        #pragma unroll
        for (int i = 0; i < 8; ++i) {
            f32x4 v = *(const f32x4*)&cbuf[srow * 260 + cseg + i * 32];
            __builtin_nontemporal_store(v, (f32x4*)(gp + cseg + i * 32));
        }
        __syncthreads();
    }
}

// ---------------- NT bf16 GEMM (128x128, m97-style) for PV / proj ----------------
// MODE 2: PV — A is fp32 attn (reg-staged + in-register bf16 cvt; r5-validated)
// MODE 3: proj (C += bias[col]) -> fp32 C (d_out)
template <int MODE>
__global__ __launch_bounds__(256) void gemm_nt(
    const void* __restrict__ Aall, const __hip_bfloat16* __restrict__ Ball,
    void* __restrict__ Call, int K,
    long sAz, long sBz, long sCz,
    const float* __restrict__ e0)
{
    constexpr bool AF32 = (MODE == 2);
    constexpr bool OF32 = (MODE == 3);

    __shared__ __align__(16) char smem[32 * 132 * 4];
    short* As = (short*)smem;
    short* Bs = (short*)(smem + 8192);
    float* cbuf = (float*)smem;

    const int tid = threadIdx.x;
    const int z = blockIdx.z;
    const int tileM = blockIdx.x, tileN = blockIdx.y;

    const short* AwB = nullptr;
    const float* AwF = nullptr;
    if constexpr (AF32) AwF = (const float*)Aall + sAz * z + (long)tileM * 128 * K;
    else                AwB = (const short*)Aall + sAz * z + (long)tileM * 128 * K;
    const short* Bw = (const short*)Ball + sBz * z + (long)tileN * 128 * K;

    const int r0s = tid >> 2, k0s = (tid & 3) * 8;
    const int r1s = r0s + 64;

    f32x4 acc[4][4];
    #pragma unroll
    for (int m = 0; m < 4; ++m)
        #pragma unroll
        for (int n = 0; n < 4; ++n) acc[m][n] = (f32x4){0.f, 0.f, 0.f, 0.f};

    const int lane = tid & 63;
    const int wave = tid >> 6;
    const int wr = (wave >> 1) * 64, wc = (wave & 1) * 64;
    const int fr = lane & 15;
    const int kb = (lane >> 4) * 8;

    const int nk = K >> 5;
    for (int kt = 0; kt < nk; ++kt) {
        if constexpr (AF32) {
            const float* Ak0 = AwF + (long)r0s * K + kt * 32 + k0s;
            const float* Ak1 = AwF + (long)r1s * K + kt * 32 + k0s;
            f32x4 a00 = *(const f32x4*)Ak0;
            f32x4 a01 = *(const f32x4*)(Ak0 + 4);
            f32x4 a10 = *(const f32x4*)Ak1;
            f32x4 a11 = *(const f32x4*)(Ak1 + 4);
            __syncthreads();                 // previous tile consumed
            short8 s0, s1;
            #pragma unroll
            for (int i = 0; i < 4; ++i) {
                s0[i] = (short)f2b_raw(a00[i]); s0[i + 4] = (short)f2b_raw(a01[i]);
                s1[i] = (short)f2b_raw(a10[i]); s1[i + 4] = (short)f2b_raw(a11[i]);
            }
            *(short8*)&As[tid * 8] = s0;
            *(short8*)&As[(tid + 256) * 8] = s1;
            gload_lds16(Bw + (long)r0s * K + kt * 32 + k0s, &Bs[tid * 8]);
            gload_lds16(Bw + (long)r1s * K + kt * 32 + k0s, &Bs[(tid + 256) * 8]);
            __syncthreads();                 // staging visible
        } else {
            __syncthreads();
            gload_lds16(AwB + (long)r0s * K + kt * 32 + k0s, &As[tid * 8]);
            gload_lds16(AwB + (long)r1s * K + kt * 32 + k0s, &As[(tid + 256) * 8]);
            gload_lds16(Bw + (long)r0s * K + kt * 32 + k0s, &Bs[tid * 8]);
            gload_lds16(Bw + (long)r1s * K + kt * 32 + k0s, &Bs[(tid + 256) * 8]);
            __syncthreads();
        }

        short8 af[4], bf[4];
        #pragma unroll
        for (int m = 0; m < 4; ++m) af[m] = *(const short8*)&As[(wr + m * 16 + fr) * 32 + kb];
        #pragma unroll
        for (int n = 0; n < 4; ++n) bf[n] = *(const short8*)&Bs[(wc + n * 16 + fr) * 32 + kb];
        #pragma unroll
        for (int m = 0; m < 4; ++m)
            #pragma unroll
            for (int n = 0; n < 4; ++n)
                acc[m][n] = __builtin_amdgcn_mfma_f32_16x16x32_bf16(af[m], bf[n], acc[m][n], 0, 0, 0);
    }

    long cbase;
    if (MODE == 2) cbase = (long)(z >> 3) * 1048576 + (long)(z & 7) * 128;
    else           cbase = sCz * z;

    float addv[4];
    #pragma unroll
    for (int n = 0; n < 4; ++n) {
        const int col = tileN * 128 + wc + n * 16 + fr;
        addv[n] = (MODE == 3) ? e0[col] : 0.f;
    }

    __syncthreads();
    #pragma unroll
    for (int q = 0; q < 4; ++q) {
        if ((wave >> 1) == (q >> 1)) {
            #pragma unroll
            for (int mm = 0; mm < 2; ++mm) {
                const int m = (q & 1) * 2 + mm;
                const int lr0 = m * 16 + (lane >> 4) * 4 - (q & 1) * 32;
                #pragma unroll
                for (int n = 0; n < 4; ++n)
                    #pragma unroll
                    for (int r = 0; r < 4; ++r)
                        cbuf[(lr0 + r) * 132 + wc + n * 16 + fr] = acc[m][n][r] + addv[n];
            }
        }
        __syncthreads();
        const long growbase = (long)tileM * 128 + q * 32;
        if constexpr (OF32) {
            float* Cg = (float*)Call + cbase;
            #pragma unroll
            for (int pass = 0; pass < 4; ++pass) {
                const int idx = (tid + pass * 256) * 4;
                const int row = idx >> 7, col = idx & 127;
                f32x4 v = *(const f32x4*)&cbuf[row * 132 + col];
                __builtin_nontemporal_store(v,
                    (f32x4*)&((float*)Call)[cbase + (growbase + row) * 1024 + tileN * 128 + col]);
                (void)Cg;
            }
        } else {
            __hip_bfloat16* Cg = (__hip_bfloat16*)Call + cbase;
            #pragma unroll
            for (int pass = 0; pass < 2; ++pass) {
                const int idx = (tid + pass * 256) * 8;
                const int row = idx >> 7, col = idx & 127;
                const float* src = &cbuf[row * 132 + col];
                f32x4 v0 = *(const f32x4*)src;
                f32x4 v1 = *(const f32x4*)(src + 4);
                short8 s;
                #pragma unroll
                for (int i = 0; i < 4; ++i) {
                    s[i] = (short)f2b_raw(v0[i]);
                    s[i + 4] = (short)f2b_raw(v1[i]);
                }
                *(short8*)&Cg[(growbase + row) * 1024 + tileN * 128 + col] = s;
            }
        }
        __syncthreads();
    }
}

extern "C" void kernel_launch(void* const* d_in, const int* in_sizes, int n_in,
                              void* d_out, int out_size, void* d_ws, size_t ws_size,
                              hipStream_t stream)
{
    const float* x  = (const float*)d_in[0];
    const float* qw = (const float*)d_in[1];
    const float* kw = (const float*)d_in[2];
    const float* vw = (const float*)d_in[3];
    const float* rw = (const float*)d_in[4];
    const float* rb = (const float*)d_in[5];
    const float* bg = (const float*)d_in[6];
    const float* bb = (const float*)d_in[7];
    const float* pw = (const float*)d_in[8];
    const float* pb = (const float*)d_in[9];

    float* outF  = (float*)d_out;          // [8,1024,1024] fp32
    float* attnF = outF + 8388608;         // [8,8,1024,1024] fp32

    char* w = (char*)d_ws;
    __hip_bfloat16* qb    = (__hip_bfloat16*)w; w += 16777216;    // [64,1024,128]
    __hip_bfloat16* kb    = (__hip_bfloat16*)w; w += 16777216;
    __hip_bfloat16* vb    = (__hip_bfloat16*)w; w += 16777216;
    __hip_bfloat16* vt    = (__hip_bfloat16*)w; w += 16777216;    // [64,128,1024]
    __hip_bfloat16* Wt    = (__hip_bfloat16*)w; w += 2097152;     // [1024,1024] reatten_w^T
    __hip_bfloat16* pWt   = (__hip_bfloat16*)w; w += 2097152;     // [1024,1024] proj_w^T
    __hip_bfloat16* o2    = (__hip_bfloat16*)w; w += 16777216;    // [8192,1024]
    float*          linv  = (float*)w;          w += 262144;      // [64,1024]
    __hip_bfloat16* Pun   = (__hip_bfloat16*)w; w += 134217728;   // [64,1024,1024]

    conv_qkv<<<8192, 256, 0, stream>>>(x, qw, kw, vw, qb, kb, vb);
    transpose_cast<float><<<dim3(32, 32, 1), 256, 0, stream>>>(rw, Wt, 1024, 1024, 0, 0);
    transpose_cast<float><<<dim3(32, 32, 1), 256, 0, stream>>>(pw, pWt, 1024, 1024, 0, 0);
    transpose_cast<__hip_bfloat16><<<dim3(4, 32, 64), 256, 0, stream>>>(vb, vt, 1024, 128, 131072, 131072);

    // P_un = exp(scale * q k^T) (NT stores), linv = 1/rowsum
    qk_softmax<<<dim3(8, 64), 256, 0, stream>>>(qb, kb, Pun, linv);
    // attn = (P_un @ W) * (1/l) * gamma/sqrt(1+eps) + (rb*gamma/sqrt(1+eps) + beta)  [fp32 only]
    gemm_reatten_256<<<dim3(4, 4, 64), 512, 0, stream>>>(Pun, Wt, attnF, bg, rb, bb, linv);
    // o2[b, i, h*128+d] = attn @ v   (A = fp32 attn, reg-staged cvt)
    gemm_nt<2><<<dim3(8, 1, 64), 256, 0, stream>>>(
        attnF, vt, o2, 1024, 1048576, 131072, 0, nullptr);
    // out = o2 @ proj_w + proj_b  (fp32, NT)
    gemm_nt<3><<<dim3(64, 8, 1), 256, 0, stream>>>(
        o2, pWt, outF, 1024, 0, 0, 0, pb);
}

// Round 17
// 368.098 us; speedup vs baseline: 1.0805x; 1.0805x over previous
//
#include <hip/hip_runtime.h>
#include <hip/hip_bf16.h>

typedef __attribute__((ext_vector_type(8))) short short8;
typedef __attribute__((ext_vector_type(4))) float f32x4;

__device__ __forceinline__ void gload_lds16(const void* g, void* l) {
    __builtin_amdgcn_global_load_lds(
        (const __attribute__((address_space(1))) void*)g,
        (__attribute__((address_space(3))) void*)l, 16, 0, 0);
}

__device__ __forceinline__ float gelu_exact(float x) {
    return 0.5f * x * (1.0f + erff(x * 0.70710678118654752f));
}
__device__ __forceinline__ unsigned short f2b_raw(float f) {
    __hip_bfloat16 h = __float2bfloat16(f);
    return *reinterpret_cast<unsigned short*>(&h);
}
__device__ __forceinline__ float tofloat(float f) { return f; }
__device__ __forceinline__ float tofloat(__hip_bfloat16 h) { return __bfloat162float(h); }

// ---------------- conv 3x3 (C=1) + exact GELU over 32x32 patches ----------------
__global__ __launch_bounds__(256) void conv_qkv(
    const float* __restrict__ x,
    const float* __restrict__ qw, const float* __restrict__ kw, const float* __restrict__ vw,
    __hip_bfloat16* __restrict__ qb, __hip_bfloat16* __restrict__ kb, __hip_bfloat16* __restrict__ vb)
{
    __shared__ float img[1024];
    const int bid = blockIdx.x;            // b*1024 + n
    const int b = bid >> 10, n = bid & 1023;
    const float* xr = x + (long)bid * 1024;
    for (int i = threadIdx.x; i < 1024; i += 256) img[i] = xr[i];
    __syncthreads();

    float wq[9], wk[9], wv[9];
    #pragma unroll
    for (int i = 0; i < 9; ++i) { wq[i] = qw[i]; wk[i] = kw[i]; wv[i] = vw[i]; }

    for (int q = 0; q < 4; ++q) {
        const int p = q * 256 + threadIdx.x;    // 0..1023 spatial
        const int r = p >> 5, c = p & 31;
        float sq = 0.f, sk = 0.f, sv = 0.f;
        #pragma unroll
        for (int dy = 0; dy < 3; ++dy) {
            const int rr = r + dy - 1;
            if (rr < 0 || rr > 31) continue;
            #pragma unroll
            for (int dx = 0; dx < 3; ++dx) {
                const int cc = c + dx - 1;
                if (cc < 0 || cc > 31) continue;
                const float px = img[rr * 32 + cc];
                sq += px * wq[dy * 3 + dx];
                sk += px * wk[dy * 3 + dx];
                sv += px * wv[dy * 3 + dx];
            }
        }
        sq = gelu_exact(sq); sk = gelu_exact(sk); sv = gelu_exact(sv);
        const int h = p >> 7, d = p & 127;
        const long off = ((long)(b * 8 + h) * 1024 + n) * 128 + d;
        qb[off] = __float2bfloat16(sq);
        kb[off] = __float2bfloat16(sk);
        vb[off] = __float2bfloat16(sv);
    }
}

// ---------------- tiled transpose + cast to bf16 ----------------
template <typename Tin>
__global__ __launch_bounds__(256) void transpose_cast(
    const Tin* __restrict__ in, __hip_bfloat16* __restrict__ out,
    int R, int Cc, long inz, long outz)
{
    __shared__ float tile[32][33];
    const long z = blockIdx.z;
    const int c0 = blockIdx.x * 32, r0 = blockIdx.y * 32;
    const int tx = threadIdx.x & 31, ty = threadIdx.x >> 5;   // 32 x 8
    const Tin* ip = in + z * inz;
    #pragma unroll
    for (int i = 0; i < 32; i += 8)
        tile[ty + i][tx] = tofloat(ip[(long)(r0 + ty + i) * Cc + (c0 + tx)]);
    __syncthreads();
    __hip_bfloat16* op = out + z * outz;
    #pragma unroll
    for (int i = 0; i < 32; i += 8)
        op[(long)(c0 + ty + i) * R + (r0 + tx)] = __float2bfloat16(tile[tx][ty + i]);
}

// ---------------- fused QK^T + exp (softmax numerator) + row-sum ----------------
__global__ __launch_bounds__(256, 2) void qk_softmax(
    const __hip_bfloat16* __restrict__ qb, const __hip_bfloat16* __restrict__ kb,
    __hip_bfloat16* __restrict__ Pun, float* __restrict__ linv)
{
    __shared__ __align__(16) char smem[74240];
    char* As = smem;                                       // [128][128] bf16 swizzled
    char* Bs = smem + 32768;                               // [128][128] bf16 swizzled
    __hip_bfloat16* pbuf = (__hip_bfloat16*)(smem + 65536); // [32][136] bounce
    float* lred = (float*)(smem + 65536);                  // reuse after last bounce

    const int tid = threadIdx.x;
    const int rt = blockIdx.x, z = blockIdx.y;
    const char* Ag = (const char*)(qb + ((long)z * 1024 + rt * 128) * 128);
    const char* Bg = (const char*)(kb + (long)z * 1024 * 128);

    int gsrc[8], pphys[8];
    #pragma unroll
    for (int i = 0; i < 8; ++i) {
        const int p = i * 4096 + tid * 16;
        const int L = p ^ (((p >> 8) & 7) << 4);   // involution
        pphys[i] = p; gsrc[i] = L;
    }
    auto STAGE = [&](const char* gb, char* lb) {
        #pragma unroll
        for (int i = 0; i < 8; ++i) gload_lds16(gb + gsrc[i], lb + pphys[i]);
    };
    auto LD8 = [&](const char* buf, int L) -> short8 {
        const int ph = L ^ (((L >> 8) & 7) << 4);
        return *(const short8*)(buf + ph);
    };

    const int lane = tid & 63, wave = tid >> 6;
    const int wr = (wave >> 1) * 64, wc = (wave & 1) * 64;
    const int fr = lane & 15, kl = lane >> 4;

    STAGE(Ag, As);
    STAGE(Bg, Bs);
    __syncthreads();

    short8 af[4][4];
    #pragma unroll
    for (int m = 0; m < 4; ++m)
        #pragma unroll
        for (int kk = 0; kk < 4; ++kk)
            af[m][kk] = LD8(As, (wr + m * 16 + fr) * 256 + (kl * 8 + kk * 32) * 2);

    float lacc[4][4];
    #pragma unroll
    for (int m = 0; m < 4; ++m)
        #pragma unroll
        for (int r = 0; r < 4; ++r) lacc[m][r] = 0.f;

    const float SCALE = 0.08838834764831843f;   // 128^-0.5

    for (int c = 0; c < 8; ++c) {
        f32x4 acc[4][4];
        #pragma unroll
        for (int m = 0; m < 4; ++m)
            #pragma unroll
            for (int n = 0; n < 4; ++n) acc[m][n] = (f32x4){0.f, 0.f, 0.f, 0.f};

        #pragma unroll
        for (int kk = 0; kk < 4; ++kk) {
            short8 bf[4];
            #pragma unroll
            for (int n = 0; n < 4; ++n)
                bf[n] = LD8(Bs, (wc + n * 16 + fr) * 256 + (kl * 8 + kk * 32) * 2);
            #pragma unroll
            for (int m = 0; m < 4; ++m)
                #pragma unroll
                for (int n = 0; n < 4; ++n)
                    acc[m][n] = __builtin_amdgcn_mfma_f32_16x16x32_bf16(af[m][kk], bf[n], acc[m][n], 0, 0, 0);
        }

        // exp in-register + row-sum accumulate (single fast exp)
        #pragma unroll
        for (int m = 0; m < 4; ++m) {
            #pragma unroll
            for (int n = 0; n < 4; ++n)
                #pragma unroll
                for (int r = 0; r < 4; ++r)
                    acc[m][n][r] = __expf(acc[m][n][r] * SCALE);
            #pragma unroll
            for (int r = 0; r < 4; ++r)
                lacc[m][r] += (acc[m][0][r] + acc[m][1][r]) + (acc[m][2][r] + acc[m][3][r]);
        }

        // bounce 32-row rounds -> coalesced bf16 NT stores; overlap next B stage
        #pragma unroll
        for (int q2 = 0; q2 < 4; ++q2) {
            if ((wave >> 1) == (q2 >> 1)) {
                #pragma unroll
                for (int mm = 0; mm < 2; ++mm) {
                    const int m = (q2 & 1) * 2 + mm;
                    const int lr0 = m * 16 + kl * 4 - (q2 & 1) * 32;
                    #pragma unroll
                    for (int n = 0; n < 4; ++n)
                        #pragma unroll
                        for (int r = 0; r < 4; ++r)
                            pbuf[(lr0 + r) * 136 + wc + n * 16 + fr] = __float2bfloat16(acc[m][n][r]);
                }
            }
            __syncthreads();
            if (q2 == 0 && c < 7) STAGE(Bg + (c + 1) * 32768, Bs);  // Bs reads retired
            #pragma unroll
            for (int p = 0; p < 2; ++p) {
                const int idx = (tid + p * 256) * 8;
                const int row = idx >> 7, col = idx & 127;
                short8 s = *(const short8*)&pbuf[row * 136 + col];
                __builtin_nontemporal_store(s,
                    (short8*)&Pun[((long)z * 1024 + rt * 128 + q2 * 32 + row) * 1024 + c * 128 + col]);
            }
            __syncthreads();   // final one drains vmcnt -> new Bs visible next iter
        }
    }

    // l reduction
    #pragma unroll
    for (int m = 0; m < 4; ++m)
        #pragma unroll
        for (int r = 0; r < 4; ++r) {
            float v = lacc[m][r];
            v += __shfl_xor(v, 1); v += __shfl_xor(v, 2);
            v += __shfl_xor(v, 4); v += __shfl_xor(v, 8);
            lacc[m][r] = v;
        }
    __syncthreads();
    if (fr == 0) {
        #pragma unroll
        for (int m = 0; m < 4; ++m)
            #pragma unroll
            for (int r = 0; r < 4; ++r)
                lred[(wr + m * 16 + kl * 4 + r) * 2 + (wave & 1)] = lacc[m][r];
    }
    __syncthreads();
    if (tid < 128) {
        const float s = lred[tid * 2] + lred[tid * 2 + 1];
        linv[(long)z * 1024 + rt * 128 + tid] = 1.0f / s;
    }
}

// ---------------- reatten 256x256 GEMM, BK=32, 4-buf depth-2, pipelined frag reads ----------------
// Rotation (race-fixed): pre-read of af/bf for tile t+1 occurs AFTER the collective
// barrier (every wave's buf-t+1 DMA landed); MFMA-upper before the barrier so bf is
// dead when overwritten. Same register count as the coarse schedule.
__global__ __launch_bounds__(512, 2) void gemm_reatten_256(
    const __hip_bfloat16* __restrict__ Sall, const __hip_bfloat16* __restrict__ Wt,
    float* __restrict__ Cout, __hip_bfloat16* __restrict__ C2out,
    const float* __restrict__ bg, const float* __restrict__ rb, const float* __restrict__ bb,
    const float* __restrict__ linv)
{
    __shared__ __align__(16) char smem[131072];
    char* ldsA = smem;            // 4 x 16384 (A: [256 rows][32 k] bf16, swizzled)
    char* ldsB = smem + 65536;    // 4 x 16384

    const int tid = threadIdx.x;
    const int z = blockIdx.z, tileM = blockIdx.x, tileN = blockIdx.y;
    const char* Ab = (const char*)(Sall + (long)z * 1048576 + (long)tileM * 256 * 1024);
    const char* Bb = (const char*)(Wt + (long)tileN * 256 * 1024);

    int grow[2], goff[2], pphys[2];
    #pragma unroll
    for (int i = 0; i < 2; ++i) {
        const int p = i * 8192 + tid * 16;
        const int l = p ^ (((p >> 7) & 3) << 4);   // involution
        pphys[i] = p; grow[i] = l >> 6; goff[i] = l & 63;
    }
    auto STAGE = [&](const char* gb, char* lb, int kt) {
        #pragma unroll
        for (int i = 0; i < 2; ++i)
            gload_lds16(gb + (long)grow[i] * 2048 + kt * 64 + goff[i], lb + pphys[i]);
    };

    const int lane = tid & 63, wid = tid >> 6;
    const int wrM = wid >> 2, wcn = wid & 3;        // 2 x 4 wave grid
    const int fr = lane & 15, kl = lane >> 4;
    const int frbase = fr * 64 + kl * 16;

    auto LD8 = [&](const char* buf, int L) -> short8 {
        const int ph = L ^ (((L >> 7) & 3) << 4);
        return *(const short8*)(buf + ph);
    };

    f32x4 acc[8][4];
    #pragma unroll
    for (int m = 0; m < 8; ++m)
        #pragma unroll
        for (int n = 0; n < 4; ++n) acc[m][n] = (f32x4){0.f, 0.f, 0.f, 0.f};

    STAGE(Ab, ldsA, 0);          STAGE(Bb, ldsB, 0);
    STAGE(Ab, ldsA + 16384, 1);  STAGE(Bb, ldsB + 16384, 1);
    asm volatile("s_waitcnt vmcnt(4)" ::: "memory");
    __builtin_amdgcn_sched_barrier(0);
    __builtin_amdgcn_s_barrier();      // all waves' tile-0 DMA landed
    __builtin_amdgcn_sched_barrier(0);

    // pre-read tile-0 lower frags (safe: after collective barrier)
    short8 bf[4], af[4], ag[4];
    #pragma unroll
    for (int n = 0; n < 4; ++n) bf[n] = LD8(ldsB, ((wcn * 64 + n * 16) * 64) + frbase);
    #pragma unroll
    for (int j = 0; j < 4; ++j) af[j] = LD8(ldsA, ((wrM * 128 + j * 16) * 64) + frbase);

    #pragma unroll 1
    for (int t = 0; t < 32; ++t) {
        char* bufA = ldsA + (t & 3) * 16384;
        const int t2 = t + 2;
        char* nA = ldsA + (t2 & 3) * 16384;
        char* nB = ldsB + (t2 & 3) * 16384;

        // upper-A reads for this tile (consumed by MFMA-upper below)
        #pragma unroll
        for (int j = 0; j < 4; ++j) ag[j] = LD8(bufA, ((wrM * 128 + 64 + j * 16) * 64) + frbase);
        if (t2 < 32) STAGE(Ab, nA, t2);
        __builtin_amdgcn_s_setprio(1);
        #pragma unroll
        for (int j = 0; j < 4; ++j)
            #pragma unroll
            for (int n = 0; n < 4; ++n)
                acc[j][n] = __builtin_amdgcn_mfma_f32_16x16x32_bf16(af[j], bf[n], acc[j][n], 0, 0, 0);
        __builtin_amdgcn_s_setprio(0);

        if (t2 < 32) STAGE(Bb, nB, t2);
        __builtin_amdgcn_s_setprio(1);
        #pragma unroll
        for (int j = 0; j < 4; ++j)
            #pragma unroll
            for (int n = 0; n < 4; ++n)
                acc[4 + j][n] = __builtin_amdgcn_mfma_f32_16x16x32_bf16(ag[j], bf[n], acc[4 + j][n], 0, 0, 0);
        __builtin_amdgcn_s_setprio(0);

        // ensure this wave's buf-(t+1) loads landed; barrier makes it collective
        if (t < 30)       { asm volatile("s_waitcnt vmcnt(4)" ::: "memory"); }
        else if (t == 30) { asm volatile("s_waitcnt vmcnt(0)" ::: "memory"); }
        __builtin_amdgcn_sched_barrier(0);
        __builtin_amdgcn_s_barrier();
        __builtin_amdgcn_sched_barrier(0);

        // pre-read next tile's lower frags (af/bf dead after MFMA-upper above)
        if (t < 31) {
            char* pA = ldsA + ((t + 1) & 3) * 16384;
            char* pB = ldsB + ((t + 1) & 3) * 16384;
            #pragma unroll
            for (int n = 0; n < 4; ++n) bf[n] = LD8(pB, ((wcn * 64 + n * 16) * 64) + frbase);
            #pragma unroll
            for (int j = 0; j < 4; ++j) af[j] = LD8(pA, ((wrM * 128 + j * 16) * 64) + frbase);
        }
    }

    // ---- epilogue: row-scale (1/l) + BN affine + LDS bounce (64x260) + dual stores ----
    __syncthreads();
    float* cbuf = (float*)smem;
    const float bninv = rsqrtf(1.0f + 1e-3f);
    float alpha[4], addv[4];
    #pragma unroll
    for (int n = 0; n < 4; ++n) {
        const int col = tileN * 256 + wcn * 64 + n * 16 + fr;
        const float g = bg[col];
        alpha[n] = g * bninv;
        addv[n] = rb[col] * alpha[n] + bb[col];
    }
    const float* linvz = linv + (long)z * 1024 + tileM * 256 + wrM * 128 + kl * 4;
    f32x4 lr[8];
    #pragma unroll
    for (int mf = 0; mf < 8; ++mf) lr[mf] = *(const f32x4*)(linvz + mf * 16);

    const int srow = tid >> 3, cseg = (tid & 7) * 4, c8 = (tid & 7) * 8;
    #pragma unroll
    for (int c = 0; c < 4; ++c) {
        if (wrM == (c >> 1)) {
            #pragma unroll
            for (int j = 0; j < 4; ++j) {
                const int mf = (c & 1) * 4 + j;
                const int lrow0 = j * 16 + kl * 4;
                #pragma unroll
                for (int n = 0; n < 4; ++n)
                    #pragma unroll
                    for (int r = 0; r < 4; ++r)
                        cbuf[(lrow0 + r) * 260 + wcn * 64 + n * 16 + fr] =
                            acc[mf][n][r] * (lr[mf][r] * alpha[n]) + addv[n];
            }
        }
        __syncthreads();
        const long gro = (long)(tileM * 256 + c * 64 + srow);
        float* gp = Cout + (long)z * 1048576 + gro * 1024 + tileN * 256;
        #pragma unroll
        for (int i = 0; i < 8; ++i) {
            f32x4 v = *(const f32x4*)&cbuf[srow * 260 + cseg + i * 32];
            __builtin_nontemporal_store(v, (f32x4*)(gp + cseg + i * 32));
        }
        __hip_bfloat16* gp2 = C2out + (long)z * 1048576 + gro * 1024 + tileN * 256;
        #pragma unroll
        for (int i = 0; i < 4; ++i) {
            const float* src = &cbuf[srow * 260 + c8 + i * 64];
            f32x4 v0 = *(const f32x4*)src;
            f32x4 v1 = *(const f32x4*)(src + 4);
            short8 s;
            #pragma unroll
            for (int k = 0; k < 4; ++k) {
                s[k] = (short)f2b_raw(v0[k]);
                s[k + 4] = (short)f2b_raw(v1[k]);
            }
            *(short8*)(gp2 + c8 + i * 64) = s;
        }
        __syncthreads();
    }
}

// ---------------- NT bf16 GEMM (128x128, m97-style) for PV / proj ----------------
template <int MODE>
__global__ __launch_bounds__(256) void gemm_nt(
    const __hip_bfloat16* __restrict__ Aall, const __hip_bfloat16* __restrict__ Ball,
    void* __restrict__ Call, int K,
    long sAz, long sBz, long sCz,
    const float* __restrict__ e0)
{
    constexpr bool OF32 = (MODE == 3);

    __shared__ __align__(16) char smem[32 * 132 * 4];
    short* As = (short*)smem;
    short* Bs = (short*)(smem + 8192);
    float* cbuf = (float*)smem;

    const int tid = threadIdx.x;
    const int z = blockIdx.z;
    const int tileM = blockIdx.x, tileN = blockIdx.y;

    const short* Aw = (const short*)Aall + sAz * z + (long)tileM * 128 * K;
    const short* Bw = (const short*)Ball + sBz * z + (long)tileN * 128 * K;

    const int r0s = tid >> 2, k0s = (tid & 3) * 8;
    const int r1s = r0s + 64;

    f32x4 acc[4][4];
    #pragma unroll
    for (int m = 0; m < 4; ++m)
        #pragma unroll
        for (int n = 0; n < 4; ++n) acc[m][n] = (f32x4){0.f, 0.f, 0.f, 0.f};

    const int lane = tid & 63;
    const int wave = tid >> 6;
    const int wr = (wave >> 1) * 64, wc = (wave & 1) * 64;
    const int fr = lane & 15;
    const int kb = (lane >> 4) * 8;

    const int nk = K >> 5;
    for (int kt = 0; kt < nk; ++kt) {
        __syncthreads();
        gload_lds16(Aw + (long)r0s * K + kt * 32 + k0s, &As[tid * 8]);
        gload_lds16(Aw + (long)r1s * K + kt * 32 + k0s, &As[(tid + 256) * 8]);
        gload_lds16(Bw + (long)r0s * K + kt * 32 + k0s, &Bs[tid * 8]);
        gload_lds16(Bw + (long)r1s * K + kt * 32 + k0s, &Bs[(tid + 256) * 8]);
        __syncthreads();

        short8 af[4], bf[4];
        #pragma unroll
        for (int m = 0; m < 4; ++m) af[m] = *(const short8*)&As[(wr + m * 16 + fr) * 32 + kb];
        #pragma unroll
        for (int n = 0; n < 4; ++n) bf[n] = *(const short8*)&Bs[(wc + n * 16 + fr) * 32 + kb];
        #pragma unroll
        for (int m = 0; m < 4; ++m)
            #pragma unroll
            for (int n = 0; n < 4; ++n)
                acc[m][n] = __builtin_amdgcn_mfma_f32_16x16x32_bf16(af[m], bf[n], acc[m][n], 0, 0, 0);
    }

    long cbase;
    if (MODE == 2) cbase = (long)(z >> 3) * 1048576 + (long)(z & 7) * 128;
    else           cbase = sCz * z;

    float addv[4];
    #pragma unroll
    for (int n = 0; n < 4; ++n) {
        const int col = tileN * 128 + wc + n * 16 + fr;
        addv[n] = (MODE == 3) ? e0[col] : 0.f;
    }

    __syncthreads();
    #pragma unroll
    for (int q = 0; q < 4; ++q) {
        if ((wave >> 1) == (q >> 1)) {
            #pragma unroll
            for (int mm = 0; mm < 2; ++mm) {
                const int m = (q & 1) * 2 + mm;
                const int lr0 = m * 16 + (lane >> 4) * 4 - (q & 1) * 32;
                #pragma unroll
                for (int n = 0; n < 4; ++n)
                    #pragma unroll
                    for (int r = 0; r < 4; ++r)
                        cbuf[(lr0 + r) * 132 + wc + n * 16 + fr] = acc[m][n][r] + addv[n];
            }
        }
        __syncthreads();
        const long growbase = (long)tileM * 128 + q * 32;
        if constexpr (OF32) {
            float* Cg = (float*)Call + cbase;
            #pragma unroll
            for (int pass = 0; pass < 4; ++pass) {
                const int idx = (tid + pass * 256) * 4;
                const int row = idx >> 7, col = idx & 127;
                f32x4 v = *(const f32x4*)&cbuf[row * 132 + col];
                __builtin_nontemporal_store(v,
                    (f32x4*)&Cg[(growbase + row) * 1024 + tileN * 128 + col]);
            }
        } else {
            __hip_bfloat16* Cg = (__hip_bfloat16*)Call + cbase;
            #pragma unroll
            for (int pass = 0; pass < 2; ++pass) {
                const int idx = (tid + pass * 256) * 8;
                const int row = idx >> 7, col = idx & 127;
                const float* src = &cbuf[row * 132 + col];
                f32x4 v0 = *(const f32x4*)src;
                f32x4 v1 = *(const f32x4*)(src + 4);
                short8 s;
                #pragma unroll
                for (int i = 0; i < 4; ++i) {
                    s[i] = (short)f2b_raw(v0[i]);
                    s[i + 4] = (short)f2b_raw(v1[i]);
                }
                *(short8*)&Cg[(growbase + row) * 1024 + tileN * 128 + col] = s;
            }
        }
        __syncthreads();
    }
}

extern "C" void kernel_launch(void* const* d_in, const int* in_sizes, int n_in,
                              void* d_out, int out_size, void* d_ws, size_t ws_size,
                              hipStream_t stream)
{
    const float* x  = (const float*)d_in[0];
    const float* qw = (const float*)d_in[1];
    const float* kw = (const float*)d_in[2];
    const float* vw = (const float*)d_in[3];
    const float* rw = (const float*)d_in[4];
    const float* rb = (const float*)d_in[5];
    const float* bg = (const float*)d_in[6];
    const float* bb = (const float*)d_in[7];
    const float* pw = (const float*)d_in[8];
    const float* pb = (const float*)d_in[9];

    float* outF  = (float*)d_out;          // [8,1024,1024] fp32
    float* attnF = outF + 8388608;         // [8,8,1024,1024] fp32

    char* w = (char*)d_ws;
    __hip_bfloat16* qb    = (__hip_bfloat16*)w; w += 16777216;    // [64,1024,128]
    __hip_bfloat16* kb    = (__hip_bfloat16*)w; w += 16777216;
    __hip_bfloat16* vb    = (__hip_bfloat16*)w; w += 16777216;
    __hip_bfloat16* vt    = (__hip_bfloat16*)w; w += 16777216;    // [64,128,1024]
    __hip_bfloat16* Wt    = (__hip_bfloat16*)w; w += 2097152;     // [1024,1024] reatten_w^T
    __hip_bfloat16* pWt   = (__hip_bfloat16*)w; w += 2097152;     // [1024,1024] proj_w^T
    __hip_bfloat16* o2    = (__hip_bfloat16*)w; w += 16777216;    // [8192,1024]
    float*          linv  = (float*)w;          w += 262144;      // [64,1024]
    __hip_bfloat16* Pun   = (__hip_bfloat16*)w; w += 134217728;   // [64,1024,1024]
    __hip_bfloat16* attnb = (__hip_bfloat16*)w; w += 134217728;   // [64,1024,1024]

    conv_qkv<<<8192, 256, 0, stream>>>(x, qw, kw, vw, qb, kb, vb);
    transpose_cast<float><<<dim3(32, 32, 1), 256, 0, stream>>>(rw, Wt, 1024, 1024, 0, 0);
    transpose_cast<float><<<dim3(32, 32, 1), 256, 0, stream>>>(pw, pWt, 1024, 1024, 0, 0);
    transpose_cast<__hip_bfloat16><<<dim3(4, 32, 64), 256, 0, stream>>>(vb, vt, 1024, 128, 131072, 131072);

    // P_un = exp(scale * q k^T) (NT stores), linv = 1/rowsum
    qk_softmax<<<dim3(8, 64), 256, 0, stream>>>(qb, kb, Pun, linv);
    // attn = (P_un @ W) * (1/l) * gamma/sqrt(1+eps) + (rb*gamma/sqrt(1+eps) + beta)
    gemm_reatten_256<<<dim3(4, 4, 64), 512, 0, stream>>>(Pun, Wt, attnF, attnb, bg, rb, bb, linv);
    // o2[b, i, h*128+d] = attn @ v
    gemm_nt<2><<<dim3(8, 1, 64), 256, 0, stream>>>(
        attnb, vt, o2, 1024, 1048576, 131072, 0, nullptr);
    // out = o2 @ proj_w + proj_b  (fp32, NT)
    gemm_nt<3><<<dim3(64, 8, 1), 256, 0, stream>>>(
        o2, pWt, outF, 1024, 0, 0, 0, pb);
}